// Round 2
// baseline (128.644 us; speedup 1.0000x reference)
//
#include <hip/hip_runtime.h>
#include <hip/hip_bf16.h>

#define BSZ  16
#define NPTS 2048
#define EDIM 256
#define QB   64   // queries per block

// ---------------------------------------------------------------------------
// Kernel 1: fold all weights into 4 E-vectors (A,B,C,D) in fp32.
//   out[b,n,e] = x*A[e] + y*B[e] + d*C[e] + D[e]
// 1024 threads: e = t&255, k-chunk h = t>>8 (4 chunks of 64), LDS reduce.
// ---------------------------------------------------------------------------
__global__ __launch_bounds__(1024) void fold_weights(
    const float* __restrict__ Wn,  // [2,E]
    const float* __restrict__ bn,  // [E]
    const float* __restrict__ Wd,  // [1,E]
    const float* __restrict__ bd,  // [E]
    const float* __restrict__ Wo,  // [2E,E]
    const float* __restrict__ bo,  // [E]
    float* __restrict__ folded)    // [4*E] = A,B,C,D
{
    __shared__ float red[4][4 * EDIM];
    const int t = threadIdx.x;
    const int e = t & (EDIM - 1);
    const int h = t >> 8;

    float a = 0.f, b = 0.f, c = 0.f, d = 0.f;
    const int k0 = h * 64;
#pragma unroll 4
    for (int kk = 0; kk < 64; ++kk) {
        const int k = k0 + kk;
        const float wt = Wo[k * EDIM + e];          // top block row k
        const float wb = Wo[(EDIM + k) * EDIM + e]; // bottom block row k
        a = fmaf(Wn[k],        wt, a);
        b = fmaf(Wn[EDIM + k], wt, b);
        d = fmaf(bn[k],        wt, d);
        c = fmaf(Wd[k],        wb, c);
        d = fmaf(bd[k],        wb, d);
    }
    red[h][0 * EDIM + e] = a;
    red[h][1 * EDIM + e] = b;
    red[h][2 * EDIM + e] = c;
    red[h][3 * EDIM + e] = d;
    __syncthreads();

    if (t < EDIM) {
        float A = red[0][0 * EDIM + e] + red[1][0 * EDIM + e] + red[2][0 * EDIM + e] + red[3][0 * EDIM + e];
        float B = red[0][1 * EDIM + e] + red[1][1 * EDIM + e] + red[2][1 * EDIM + e] + red[3][1 * EDIM + e];
        float C = red[0][2 * EDIM + e] + red[1][2 * EDIM + e] + red[2][2 * EDIM + e] + red[3][2 * EDIM + e];
        float D = red[0][3 * EDIM + e] + red[1][3 * EDIM + e] + red[2][3 * EDIM + e] + red[3][3 * EDIM + e];
        D += bo[e];
        folded[0 * EDIM + e] = A;
        folded[1 * EDIM + e] = B;
        folded[2 * EDIM + e] = C;
        folded[3 * EDIM + e] = D;
    }
}

// ---------------------------------------------------------------------------
// Kernel 2: per block — compact probe points of batch b into LDS, compute
// min-dist for QB=64 queries (4 threads/query, contiguous chunks, wave-uniform
// broadcast LDS reads), then emit out[b,n,:] = x*A + y*B + d*C + D as fp32
// with float4 coalesced stores.
// Grid = BSZ * (NPTS/QB) = 16*32 = 512 blocks, 256 threads.
// ---------------------------------------------------------------------------
__global__ __launch_bounds__(256) void mdpp_main(
    const float* __restrict__ locs,   // [B,N,2] fp32
    const int*   __restrict__ probe,  // [B,N] (bool as int32)
    const float* __restrict__ folded, // [4*E]
    float*       __restrict__ out)    // [B,N,E] fp32
{
    __shared__ float2 plist[NPTS];
    __shared__ int    pcount;
    __shared__ float  partmin[4][QB];
    __shared__ float  xq[QB], yq[QB], dq[QB];

    const int t   = threadIdx.x;
    const int bid = blockIdx.x;
    const int b   = bid >> 5;           // NPTS/QB = 32 tiles per batch
    const int n0  = (bid & 31) * QB;

    // Hoist the folded-vector loads: issue global loads early, use in phase 2.
    const int e0 = (t & 31) * 8;
    float A[8], Bv[8], C[8], D[8];
#pragma unroll
    for (int i = 0; i < 8; ++i) {
        A[i]  = folded[0 * EDIM + e0 + i];
        Bv[i] = folded[1 * EDIM + e0 + i];
        C[i]  = folded[2 * EDIM + e0 + i];
        D[i]  = folded[3 * EDIM + e0 + i];
    }

    if (t == 0) pcount = 0;
    __syncthreads();

    const float2* lb = reinterpret_cast<const float2*>(locs) + (size_t)b * NPTS;

    // Compact probe coords into LDS (order irrelevant for min).
#pragma unroll
    for (int jj = 0; jj < NPTS / 256; ++jj) {
        const int j = jj * 256 + t;
        if (probe[b * NPTS + j] != 0) {
            const int idx = atomicAdd(&pcount, 1);
            plist[idx] = lb[j];
        }
    }
    // Query coords for this tile.
    if (t < QB) {
        const float2 p = lb[n0 + t];
        xq[t] = p.x;
        yq[t] = p.y;
    }
    __syncthreads();

    const int M = pcount;
    const int q = t & (QB - 1);
    const int h = t >> 6;               // wave index: uniform per wave
    const float x = xq[q], y = yq[q];

    float best = 3.0e38f;
    const int lo = (M * h) >> 2;
    const int hi = (M * (h + 1)) >> 2;
#pragma unroll 4
    for (int j = lo; j < hi; ++j) {
        const float2 p = plist[j];      // wave-uniform addr -> LDS broadcast
        const float dx = x - p.x;
        const float dy = y - p.y;
        const float d2 = fmaf(dy, dy, dx * dx);
        best = fminf(best, d2);
    }
    partmin[h][q] = best;
    __syncthreads();

    if (t < QB) {
        const float m = fminf(fminf(partmin[0][t], partmin[1][t]),
                              fminf(partmin[2][t], partmin[3][t]));
        dq[t] = sqrtf(m);               // exact 0 when query is itself a probe
    }
    __syncthreads();

    // Phase 2: thread owns e0..e0+7; 8 query-rows per iteration.
    const int qh = t >> 5;              // 0..7
#pragma unroll
    for (int it = 0; it < 8; ++it) {
        const int qq = it * 8 + qh;
        const float xx = xq[qq], yy = yq[qq], dd = dq[qq];
        float4 st0, st1;
        st0.x = fmaf(xx, A[0], fmaf(yy, Bv[0], fmaf(dd, C[0], D[0])));
        st0.y = fmaf(xx, A[1], fmaf(yy, Bv[1], fmaf(dd, C[1], D[1])));
        st0.z = fmaf(xx, A[2], fmaf(yy, Bv[2], fmaf(dd, C[2], D[2])));
        st0.w = fmaf(xx, A[3], fmaf(yy, Bv[3], fmaf(dd, C[3], D[3])));
        st1.x = fmaf(xx, A[4], fmaf(yy, Bv[4], fmaf(dd, C[4], D[4])));
        st1.y = fmaf(xx, A[5], fmaf(yy, Bv[5], fmaf(dd, C[5], D[5])));
        st1.z = fmaf(xx, A[6], fmaf(yy, Bv[6], fmaf(dd, C[6], D[6])));
        st1.w = fmaf(xx, A[7], fmaf(yy, Bv[7], fmaf(dd, C[7], D[7])));
        float* op = out + ((size_t)(b * NPTS + n0 + qq) * EDIM + e0);
        *reinterpret_cast<float4*>(op)     = st0;
        *reinterpret_cast<float4*>(op + 4) = st1;
    }
}

extern "C" void kernel_launch(void* const* d_in, const int* in_sizes, int n_in,
                              void* d_out, int out_size, void* d_ws, size_t ws_size,
                              hipStream_t stream) {
    const float* locs  = (const float*)d_in[0];
    const int*   probe = (const int*)d_in[1];
    const float* Wn = (const float*)d_in[2];
    const float* bn = (const float*)d_in[3];
    const float* Wd = (const float*)d_in[4];
    const float* bd = (const float*)d_in[5];
    const float* Wo = (const float*)d_in[6];
    const float* bo = (const float*)d_in[7];
    float* out = (float*)d_out;

    float* folded = (float*)d_ws;  // 4*EDIM floats = 4 KB scratch

    fold_weights<<<1, 1024, 0, stream>>>(Wn, bn, Wd, bd, Wo, bo, folded);
    mdpp_main<<<BSZ * (NPTS / QB), 256, 0, stream>>>(locs, probe, folded, out);
}

// Round 3
// 95.731 us; speedup vs baseline: 1.3438x; 1.3438x over previous
//
#include <hip/hip_runtime.h>
#include <hip/hip_bf16.h>

#define BSZ  16
#define NPTS 2048
#define EDIM 256
#define QB   64     // queries per block
#define FPB  16     // fold partial blocks

// ---------------------------------------------------------------------------
// Kernel 1: partial weight-fold. Block i handles k-rows [16i,16i+16) of the
// top half of Wo and the same rows of the bottom half. Writes partials
// ws[i][4][256] (A,B,C,D slices). 16 blocks x 256 threads, coalesced reads.
//   out[b,n,e] = x*A[e] + y*B[e] + d*C[e] + D[e]
// ---------------------------------------------------------------------------
__global__ __launch_bounds__(256) void fold_part(
    const float* __restrict__ Wn,  // [2,E]
    const float* __restrict__ bn,  // [E]
    const float* __restrict__ Wd,  // [1,E]
    const float* __restrict__ bd,  // [E]
    const float* __restrict__ Wo,  // [2E,E]
    float* __restrict__ ws)        // [FPB][4*E] partials
{
    const int e   = threadIdx.x;
    const int blk = blockIdx.x;
    float a = 0.f, b = 0.f, c = 0.f, d = 0.f;
#pragma unroll
    for (int kk = 0; kk < EDIM / FPB; ++kk) {
        const int k = blk * (EDIM / FPB) + kk;
        const float wt = Wo[k * EDIM + e];          // top block row k (coalesced)
        const float wb = Wo[(EDIM + k) * EDIM + e]; // bottom block row k
        a = fmaf(Wn[k],        wt, a);              // Wn/bn/Wd/bd: scalar loads
        b = fmaf(Wn[EDIM + k], wt, b);
        d = fmaf(bn[k],        wt, d);
        c = fmaf(Wd[k],        wb, c);
        d = fmaf(bd[k],        wb, d);
    }
    float* o = ws + blk * 4 * EDIM;
    o[0 * EDIM + e] = a;
    o[1 * EDIM + e] = b;
    o[2 * EDIM + e] = c;
    o[3 * EDIM + e] = d;
}

// ---------------------------------------------------------------------------
// Kernel 2: per block — compact probe points of batch b into LDS, reduce the
// fold partials into folded_lds (cooperative, 64 coalesced L2 loads/thread),
// compute min-dist for QB=64 queries (4 threads/query, float4 pair reads,
// wave-uniform broadcast), then emit out[b,n,:] = x*A + y*B + d*C + D with
// float4 stores. Grid = BSZ * (NPTS/QB) = 512 blocks, 256 threads.
// ---------------------------------------------------------------------------
__global__ __launch_bounds__(256) void mdpp_main(
    const float* __restrict__ locs,   // [B,N,2] fp32
    const int*   __restrict__ probe,  // [B,N] (bool as int32)
    const float* __restrict__ ws,     // [FPB][4*E] fold partials
    const float* __restrict__ bo,     // [E]
    float*       __restrict__ out)    // [B,N,E] fp32
{
    __shared__ __align__(16) float2 plist[NPTS + 2];
    __shared__ float  folded_lds[4 * EDIM];
    __shared__ int    pcount;
    __shared__ float  partmin[4][QB];
    __shared__ float  xq[QB], yq[QB], dq[QB];

    const int t   = threadIdx.x;
    const int bid = blockIdx.x;
    const int b   = bid >> 5;           // NPTS/QB = 32 tiles per batch
    const int n0  = (bid & 31) * QB;

    if (t == 0) pcount = 0;
    __syncthreads();

    const float2* lb = reinterpret_cast<const float2*>(locs) + (size_t)b * NPTS;

    // Compact probe coords into LDS (order irrelevant for min).
#pragma unroll
    for (int jj = 0; jj < NPTS / 256; ++jj) {
        const int j = jj * 256 + t;
        if (probe[b * NPTS + j] != 0) {
            const int idx = atomicAdd(&pcount, 1);
            plist[idx] = lb[j];
        }
    }
    // Query coords for this tile.
    if (t < QB) {
        const float2 p = lb[n0 + t];
        xq[t] = p.x;
        yq[t] = p.y;
    }
    __syncthreads();

    // Sentinel so odd M needs no tail code (dist ~1e38 never wins the min).
    if (t == 0) plist[pcount] = make_float2(1.0e19f, 1.0e19f);

    // Cooperative reduce of fold partials: thread t owns column t of each of
    // the 4 folded vectors. 64 coalesced loads (L2-resident after fold_part).
#pragma unroll
    for (int v = 0; v < 4; ++v) {
        float s = 0.f;
#pragma unroll
        for (int p = 0; p < FPB; ++p) s += ws[p * 4 * EDIM + v * EDIM + t];
        if (v == 3) s += bo[t];
        folded_lds[v * EDIM + t] = s;
    }
    __syncthreads();   // sentinel + folded_lds visible

    const int M = pcount;
    const int q = t & (QB - 1);
    const int h = t >> 6;               // wave index: uniform per wave
    const float x = xq[q], y = yq[q];

    float best = 3.0e38f;
    const int npair = (M + 1) >> 1;
    const int lo = (npair * h) >> 2;
    const int hi = (npair * (h + 1)) >> 2;
    const float4* pl4 = reinterpret_cast<const float4*>(plist);
#pragma unroll 2
    for (int j = lo; j < hi; ++j) {
        const float4 pp = pl4[j];       // wave-uniform addr -> LDS broadcast
        const float dx0 = x - pp.x, dy0 = y - pp.y;
        const float dx1 = x - pp.z, dy1 = y - pp.w;
        best = fminf(best, fmaf(dy0, dy0, dx0 * dx0));
        best = fminf(best, fmaf(dy1, dy1, dx1 * dx1));
    }
    partmin[h][q] = best;
    __syncthreads();

    if (t < QB) {
        const float m = fminf(fminf(partmin[0][t], partmin[1][t]),
                              fminf(partmin[2][t], partmin[3][t]));
        dq[t] = sqrtf(m);               // exact 0 when query is itself a probe
    }
    __syncthreads();

    // Phase 2: thread owns e0..e0+7; 8 query-rows per iteration.
    const int e0 = (t & 31) * 8;
    float A[8], Bv[8], C[8], D[8];
#pragma unroll
    for (int i = 0; i < 8; ++i) {
        A[i]  = folded_lds[0 * EDIM + e0 + i];
        Bv[i] = folded_lds[1 * EDIM + e0 + i];
        C[i]  = folded_lds[2 * EDIM + e0 + i];
        D[i]  = folded_lds[3 * EDIM + e0 + i];
    }
    const int qh = t >> 5;              // 0..7
#pragma unroll
    for (int it = 0; it < 8; ++it) {
        const int qq = it * 8 + qh;
        const float xx = xq[qq], yy = yq[qq], dd = dq[qq];
        float4 st0, st1;
        st0.x = fmaf(xx, A[0], fmaf(yy, Bv[0], fmaf(dd, C[0], D[0])));
        st0.y = fmaf(xx, A[1], fmaf(yy, Bv[1], fmaf(dd, C[1], D[1])));
        st0.z = fmaf(xx, A[2], fmaf(yy, Bv[2], fmaf(dd, C[2], D[2])));
        st0.w = fmaf(xx, A[3], fmaf(yy, Bv[3], fmaf(dd, C[3], D[3])));
        st1.x = fmaf(xx, A[4], fmaf(yy, Bv[4], fmaf(dd, C[4], D[4])));
        st1.y = fmaf(xx, A[5], fmaf(yy, Bv[5], fmaf(dd, C[5], D[5])));
        st1.z = fmaf(xx, A[6], fmaf(yy, Bv[6], fmaf(dd, C[6], D[6])));
        st1.w = fmaf(xx, A[7], fmaf(yy, Bv[7], fmaf(dd, C[7], D[7])));
        float* op = out + ((size_t)(b * NPTS + n0 + qq) * EDIM + e0);
        *reinterpret_cast<float4*>(op)     = st0;
        *reinterpret_cast<float4*>(op + 4) = st1;
    }
}

extern "C" void kernel_launch(void* const* d_in, const int* in_sizes, int n_in,
                              void* d_out, int out_size, void* d_ws, size_t ws_size,
                              hipStream_t stream) {
    const float* locs  = (const float*)d_in[0];
    const int*   probe = (const int*)d_in[1];
    const float* Wn = (const float*)d_in[2];
    const float* bn = (const float*)d_in[3];
    const float* Wd = (const float*)d_in[4];
    const float* bd = (const float*)d_in[5];
    const float* Wo = (const float*)d_in[6];
    const float* bo = (const float*)d_in[7];
    float* out = (float*)d_out;

    float* partials = (float*)d_ws;  // FPB * 4*EDIM floats = 64 KB scratch

    fold_part<<<FPB, 256, 0, stream>>>(Wn, bn, Wd, bd, Wo, partials);
    mdpp_main<<<BSZ * (NPTS / QB), 256, 0, stream>>>(locs, probe, partials, bo, out);
}

// Round 4
// 90.900 us; speedup vs baseline: 1.4152x; 1.0531x over previous
//
#include <hip/hip_runtime.h>

#define BSZ  16
#define NPTS 2048
#define EDIM 256
#define QB   64     // queries per main-kernel block
#define FPB  16     // fold partial blocks

// ws layout (bytes):
//   [0,       65536)  : fold partials [FPB][4*EDIM] floats
//   [65536,   65792)  : per-batch probe counts (16 ints, padded)
//   [65792, 65792+16*NPTS*8) : per-batch compacted probe lists (float2)

// ---------------------------------------------------------------------------
// Kernel 1 (prep), 32 blocks x 256 threads:
//   blocks 0..15  : partial weight-fold (block i does k-rows [16i,16i+16))
//   blocks 16..31 : ballot-scan probe compaction for batch (blk-16)
// out[b,n,e] = x*A[e] + y*B[e] + d*C[e] + D[e] after the fold collapse.
// ---------------------------------------------------------------------------
__global__ __launch_bounds__(256) void prep(
    const float* __restrict__ Wn,   // [2,E]
    const float* __restrict__ bn,   // [E]
    const float* __restrict__ Wd,   // [1,E]
    const float* __restrict__ bd,   // [E]
    const float* __restrict__ Wo,   // [2E,E]
    const float* __restrict__ locs, // [B,N,2]
    const int*   __restrict__ probe,// [B,N]
    float*  __restrict__ partials,  // [FPB][4*E]
    int*    __restrict__ gcnt,      // [B]
    float2* __restrict__ glist)     // [B][NPTS]
{
    __shared__ int cnt;
    const int t   = threadIdx.x;
    const int blk = blockIdx.x;

    if (blk < FPB) {
        // ---- weight fold slice ----
        const int e = t;
        float a = 0.f, b = 0.f, c = 0.f, d = 0.f;
#pragma unroll
        for (int kk = 0; kk < EDIM / FPB; ++kk) {
            const int k = blk * (EDIM / FPB) + kk;
            const float wt = Wo[k * EDIM + e];          // coalesced
            const float wb = Wo[(EDIM + k) * EDIM + e];
            a = fmaf(Wn[k],        wt, a);
            b = fmaf(Wn[EDIM + k], wt, b);
            d = fmaf(bn[k],        wt, d);
            c = fmaf(Wd[k],        wb, c);
            d = fmaf(bd[k],        wb, d);
        }
        float* o = partials + blk * 4 * EDIM;
        o[0 * EDIM + e] = a;
        o[1 * EDIM + e] = b;
        o[2 * EDIM + e] = c;
        o[3 * EDIM + e] = d;
    } else {
        // ---- probe compaction via ballot scan (order irrelevant for min) ----
        const int b = blk - FPB;
        if (t == 0) cnt = 0;
        __syncthreads();
        const float2* lb = reinterpret_cast<const float2*>(locs) + (size_t)b * NPTS;
        float2* gl = glist + (size_t)b * NPTS;
        const int lane = t & 63;
#pragma unroll
        for (int jj = 0; jj < NPTS / 256; ++jj) {
            const int j = jj * 256 + t;
            const float2 p = lb[j];                          // coalesced
            const bool pred = probe[b * NPTS + j] != 0;
            const unsigned long long mb = __ballot(pred);
            const int rank = __popcll(mb & ((1ull << lane) - 1ull));
            int base = 0;
            if (lane == 0) base = atomicAdd(&cnt, __popcll(mb));
            base = __shfl(base, 0);
            if (pred) gl[base + rank] = p;
        }
        __syncthreads();
        if (t == 0) gcnt[b] = cnt;
    }
}

// ---------------------------------------------------------------------------
// Kernel 2 (main), 512 blocks x 256 threads, QB=64 queries/block.
//  - coalesced load of compacted probe list -> LDS (no atomics)
//  - reduce fold partials -> folded_lds
//  - min-dist: 4 queries/thread, 16 chunks; each float4 LDS read serves
//    8 distance evals (4 queries x 2 points)
//  - store: lane owns 4 consecutive floats; each wave stores one full
//    contiguous 1 KB output row per iteration
// ---------------------------------------------------------------------------
__global__ __launch_bounds__(256) void mdpp_main(
    const float*  __restrict__ locs,     // [B,N,2]
    const float*  __restrict__ partials, // [FPB][4*E]
    const int*    __restrict__ gcnt,     // [B]
    const float2* __restrict__ glist,    // [B][NPTS]
    const float*  __restrict__ bo,       // [E]
    float*        __restrict__ out)      // [B,N,E]
{
    __shared__ __align__(16) float2 pl[NPTS + 32];
    __shared__ float folded[4 * EDIM];
    __shared__ float partmin[16][QB];
    __shared__ float xq[QB], yq[QB], dq[QB];

    const int t    = threadIdx.x;
    const int bid  = blockIdx.x;
    const int b    = bid >> 5;            // 32 tiles per batch
    const int n0   = (bid & 31) * QB;
    const int lane = t & 63;
    const int w    = t >> 6;

    const int M  = gcnt[b];               // broadcast load
    const int Mp = (M + 31) & ~31;        // pad to x32 points (16 even chunks)

    // Compacted list -> LDS, coalesced; sentinel-pad the tail.
    const float2* gl = glist + (size_t)b * NPTS;
    for (int i = t; i < M; i += 256) pl[i] = gl[i];
    if (t < Mp - M) pl[M + t] = make_float2(1.0e19f, 1.0e19f);

    // Reduce fold partials: thread t owns column t of each folded vector.
#pragma unroll
    for (int v = 0; v < 4; ++v) {
        float s = 0.f;
#pragma unroll
        for (int p = 0; p < FPB; ++p) s += partials[p * 4 * EDIM + v * EDIM + t];
        if (v == 3) s += bo[t];
        folded[v * EDIM + t] = s;
    }

    // Query coords for this tile.
    if (t < QB) {
        const float2 p = reinterpret_cast<const float2*>(locs)[(size_t)b * NPTS + n0 + t];
        xq[t] = p.x;
        yq[t] = p.y;
    }
    __syncthreads();

    // ---- min-dist: 4 queries/thread, chunk = quarter-wave group ----
    const int qb    = lane & 15;          // query sub-index
    const int chunk = w * 4 + (lane >> 4);// 0..15
    float qx[4], qy[4], best[4];
#pragma unroll
    for (int j = 0; j < 4; ++j) {
        qx[j] = xq[j * 16 + qb];
        qy[j] = yq[j * 16 + qb];
        best[j] = 3.0e38f;
    }
    const int S2 = Mp >> 5;               // float4 pairs per chunk
    const float4* pl4 = reinterpret_cast<const float4*>(pl);
    const int lo = chunk * S2, hi = lo + S2;
#pragma unroll 2
    for (int i = lo; i < hi; ++i) {
        const float4 pp = pl4[i];
#pragma unroll
        for (int j = 0; j < 4; ++j) {
            const float dx0 = qx[j] - pp.x, dy0 = qy[j] - pp.y;
            const float dx1 = qx[j] - pp.z, dy1 = qy[j] - pp.w;
            best[j] = fminf(best[j], fmaf(dy0, dy0, dx0 * dx0));
            best[j] = fminf(best[j], fmaf(dy1, dy1, dx1 * dx1));
        }
    }
#pragma unroll
    for (int j = 0; j < 4; ++j) partmin[chunk][j * 16 + qb] = best[j];
    __syncthreads();

    if (t < QB) {
        float m = partmin[0][t];
#pragma unroll
        for (int c = 1; c < 16; ++c) m = fminf(m, partmin[c][t]);
        dq[t] = sqrtf(m);                 // exact 0 when query is itself a probe
    }
    __syncthreads();

    // ---- emit: lane owns e in [4*lane, 4*lane+4); wave stores 1 KB rows ----
    const int e0 = lane * 4;
    float A[4], Bv[4], C[4], D[4];
#pragma unroll
    for (int i = 0; i < 4; ++i) {
        A[i]  = folded[0 * EDIM + e0 + i];
        Bv[i] = folded[1 * EDIM + e0 + i];
        C[i]  = folded[2 * EDIM + e0 + i];
        D[i]  = folded[3 * EDIM + e0 + i];
    }
#pragma unroll
    for (int it = 0; it < 16; ++it) {
        const int r = it * 4 + w;         // row within tile, uniform per wave
        const float xx = xq[r], yy = yq[r], dd = dq[r];
        float4 st;
        st.x = fmaf(xx, A[0], fmaf(yy, Bv[0], fmaf(dd, C[0], D[0])));
        st.y = fmaf(xx, A[1], fmaf(yy, Bv[1], fmaf(dd, C[1], D[1])));
        st.z = fmaf(xx, A[2], fmaf(yy, Bv[2], fmaf(dd, C[2], D[2])));
        st.w = fmaf(xx, A[3], fmaf(yy, Bv[3], fmaf(dd, C[3], D[3])));
        *reinterpret_cast<float4*>(
            out + ((size_t)(b * NPTS + n0 + r) * EDIM + e0)) = st;
    }
}

extern "C" void kernel_launch(void* const* d_in, const int* in_sizes, int n_in,
                              void* d_out, int out_size, void* d_ws, size_t ws_size,
                              hipStream_t stream) {
    const float* locs  = (const float*)d_in[0];
    const int*   probe = (const int*)d_in[1];
    const float* Wn = (const float*)d_in[2];
    const float* bn = (const float*)d_in[3];
    const float* Wd = (const float*)d_in[4];
    const float* bd = (const float*)d_in[5];
    const float* Wo = (const float*)d_in[6];
    const float* bo = (const float*)d_in[7];
    float* out = (float*)d_out;

    float*  partials = (float*)d_ws;                          // 64 KB
    int*    gcnt     = (int*)((char*)d_ws + 65536);           // 64 B (padded to 256)
    float2* glist    = (float2*)((char*)d_ws + 65792);        // 16*2048*8 = 256 KB

    prep<<<2 * FPB, 256, 0, stream>>>(Wn, bn, Wd, bd, Wo, locs, probe,
                                      partials, gcnt, glist);
    mdpp_main<<<BSZ * (NPTS / QB), 256, 0, stream>>>(locs, partials, gcnt,
                                                     glist, bo, out);
}

// Round 5
// 89.613 us; speedup vs baseline: 1.4355x; 1.0144x over previous
//
#include <hip/hip_runtime.h>

#define BSZ  16
#define NPTS 2048
#define EDIM 256
#define QB   64     // queries per main-kernel block
#define FPB  16     // fold partial blocks

// ---------------------------------------------------------------------------
// Kernel 1 (prep): partial weight-fold only. Block i handles k-rows
// [16i,16i+16) of both halves of Wo; writes partials ws[i][4][256].
// After the algebraic collapse: out[b,n,e] = x*A[e] + y*B[e] + d*C[e] + D[e].
// ---------------------------------------------------------------------------
__global__ __launch_bounds__(256) void fold_part(
    const float* __restrict__ Wn,  // [2,E]
    const float* __restrict__ bn,  // [E]
    const float* __restrict__ Wd,  // [1,E]
    const float* __restrict__ bd,  // [E]
    const float* __restrict__ Wo,  // [2E,E]
    float* __restrict__ ws)        // [FPB][4*E] partials
{
    const int e   = threadIdx.x;
    const int blk = blockIdx.x;
    float a = 0.f, b = 0.f, c = 0.f, d = 0.f;
#pragma unroll
    for (int kk = 0; kk < EDIM / FPB; ++kk) {
        const int k = blk * (EDIM / FPB) + kk;
        const float wt = Wo[k * EDIM + e];          // coalesced
        const float wb = Wo[(EDIM + k) * EDIM + e];
        a = fmaf(Wn[k],        wt, a);
        b = fmaf(Wn[EDIM + k], wt, b);
        d = fmaf(bn[k],        wt, d);
        c = fmaf(Wd[k],        wb, c);
        d = fmaf(bd[k],        wb, d);
    }
    float* o = ws + blk * 4 * EDIM;
    o[0 * EDIM + e] = a;
    o[1 * EDIM + e] = b;
    o[2 * EDIM + e] = c;
    o[3 * EDIM + e] = d;
}

// ---------------------------------------------------------------------------
// Kernel 2 (main), 512 blocks x 256 threads, QB=64 queries/block.
//  - fold-partial reduce -> folded (L2, issued first)
//  - per-block ballot-scan probe compaction into LDS as (px,py,s_p,0)
//  - min-dist in expanded form: min_p(s_p - 2x*px - 2y*py), + s_q at end.
//    Wave owns a quarter of the list; its 4 quads read CONSECUTIVE float4s
//    (banks 0..15, conflict-free, broadcast within quad). 4 queries/thread.
//  - emit: lane owns 4 consecutive e; wave stores contiguous 1 KB rows
// ---------------------------------------------------------------------------
__global__ __launch_bounds__(256) void mdpp_main(
    const float* __restrict__ locs,     // [B,N,2]
    const int*   __restrict__ probe,    // [B,N] (bool as int32)
    const float* __restrict__ partials, // [FPB][4*E]
    const float* __restrict__ bo,       // [E]
    float*       __restrict__ out)      // [B,N,E]
{
    __shared__ __align__(16) float4 pl[NPTS + 16];
    __shared__ float folded[4 * EDIM];
    __shared__ float partmin[16][QB];
    __shared__ float xq[QB], yq[QB], sq[QB], dq[QB];
    __shared__ int   cnt;

    const int t    = threadIdx.x;
    const int bid  = blockIdx.x;
    const int b    = bid >> 5;            // 32 tiles per batch
    const int n0   = (bid & 31) * QB;
    const int lane = t & 63;
    const int w    = t >> 6;
    const int quad = lane >> 4;
    const int ql   = lane & 15;

    if (t == 0) cnt = 0;

    // Fold-partial reduce: thread t owns column t of each folded vector.
    {
        float s0 = 0.f, s1 = 0.f, s2 = 0.f, s3 = 0.f;
#pragma unroll
        for (int p = 0; p < FPB; ++p) {
            const float* pp = partials + p * 4 * EDIM;
            s0 += pp[0 * EDIM + t];
            s1 += pp[1 * EDIM + t];
            s2 += pp[2 * EDIM + t];
            s3 += pp[3 * EDIM + t];
        }
        folded[0 * EDIM + t] = s0;
        folded[1 * EDIM + t] = s1;
        folded[2 * EDIM + t] = s2;
        folded[3 * EDIM + t] = s3 + bo[t];
    }

    const float2* lb = reinterpret_cast<const float2*>(locs) + (size_t)b * NPTS;

    // Query coords + squared norms for this tile.
    if (t < QB) {
        const float2 p = lb[n0 + t];
        xq[t] = p.x;
        yq[t] = p.y;
        sq[t] = fmaf(p.x, p.x, p.y * p.y);
    }
    __syncthreads();          // cnt=0 visible before atomics

    // Ballot-scan compaction (order irrelevant for min).
#pragma unroll
    for (int jj = 0; jj < NPTS / 256; ++jj) {
        const int j = jj * 256 + t;
        const float2 p = lb[j];                       // coalesced
        const bool pred = probe[b * NPTS + j] != 0;
        const unsigned long long mb = __ballot(pred);
        const int rank = __popcll(mb & ((1ull << lane) - 1ull));
        int base = 0;
        if (lane == 0) base = atomicAdd(&cnt, __popcll(mb));
        base = __shfl(base, 0);
        if (pred) pl[base + rank] =
            make_float4(p.x, p.y, fmaf(p.x, p.x, p.y * p.y), 0.f);
    }
    __syncthreads();

    const int M  = cnt;
    const int Mp = (M + 15) & ~15;       // pad to x16 (4 waves x 4 quads)
    if (t < Mp - M) pl[M + t] = make_float4(0.f, 0.f, 1.0e19f, 0.f);
    __syncthreads();

    // ---- min-dist: wave w owns quarter [w*Q4, (w+1)*Q4) ----
    const int Q4   = Mp >> 2;
    const int it_n = Q4 >> 2;            // points per quad
    const float4* base4 = pl + w * Q4 + quad;
    float ax[4], ay[4], bm[4];
#pragma unroll
    for (int j = 0; j < 4; ++j) {
        const int q = j * 16 + ql;
        ax[j] = -2.0f * xq[q];
        ay[j] = -2.0f * yq[q];
        bm[j] = 3.0e38f;
    }
#pragma unroll 4
    for (int i = 0; i < it_n; ++i) {
        const float4 pp = base4[i * 4];  // 4 quads -> 4 consecutive float4s
#pragma unroll
        for (int j = 0; j < 4; ++j) {
            float d2 = fmaf(ax[j], pp.x, pp.z);
            d2 = fmaf(ay[j], pp.y, d2);
            bm[j] = fminf(bm[j], d2);
        }
    }
#pragma unroll
    for (int j = 0; j < 4; ++j) partmin[w * 4 + quad][j * 16 + ql] = bm[j];
    __syncthreads();

    if (t < QB) {
        float m = partmin[0][t];
#pragma unroll
        for (int c = 1; c < 16; ++c) m = fminf(m, partmin[c][t]);
        dq[t] = sqrtf(fmaxf(m + sq[t], 0.f));   // clamp like the reference
    }
    __syncthreads();

    // ---- emit: lane owns e in [4*lane, 4*lane+4); wave stores 1 KB rows ----
    const int e0 = lane * 4;
    float A[4], Bv[4], C[4], D[4];
#pragma unroll
    for (int i = 0; i < 4; ++i) {
        A[i]  = folded[0 * EDIM + e0 + i];
        Bv[i] = folded[1 * EDIM + e0 + i];
        C[i]  = folded[2 * EDIM + e0 + i];
        D[i]  = folded[3 * EDIM + e0 + i];
    }
#pragma unroll
    for (int it = 0; it < 16; ++it) {
        const int r = it * 4 + w;        // row within tile, uniform per wave
        const float xx = xq[r], yy = yq[r], dd = dq[r];
        float4 st;
        st.x = fmaf(xx, A[0], fmaf(yy, Bv[0], fmaf(dd, C[0], D[0])));
        st.y = fmaf(xx, A[1], fmaf(yy, Bv[1], fmaf(dd, C[1], D[1])));
        st.z = fmaf(xx, A[2], fmaf(yy, Bv[2], fmaf(dd, C[2], D[2])));
        st.w = fmaf(xx, A[3], fmaf(yy, Bv[3], fmaf(dd, C[3], D[3])));
        *reinterpret_cast<float4*>(
            out + ((size_t)(b * NPTS + n0 + r) * EDIM + e0)) = st;
    }
}

extern "C" void kernel_launch(void* const* d_in, const int* in_sizes, int n_in,
                              void* d_out, int out_size, void* d_ws, size_t ws_size,
                              hipStream_t stream) {
    const float* locs  = (const float*)d_in[0];
    const int*   probe = (const int*)d_in[1];
    const float* Wn = (const float*)d_in[2];
    const float* bn = (const float*)d_in[3];
    const float* Wd = (const float*)d_in[4];
    const float* bd = (const float*)d_in[5];
    const float* Wo = (const float*)d_in[6];
    const float* bo = (const float*)d_in[7];
    float* out = (float*)d_out;

    float* partials = (float*)d_ws;  // FPB * 4*EDIM floats = 64 KB scratch

    fold_part<<<FPB, 256, 0, stream>>>(Wn, bn, Wd, bd, Wo, partials);
    mdpp_main<<<BSZ * (NPTS / QB), 256, 0, stream>>>(locs, probe, partials,
                                                     bo, out);
}